// Round 1
// baseline (168.301 us; speedup 1.0000x reference)
//
#include <hip/hip_runtime.h>

#define N_IN   20000
#define N_OUT  20000
#define NEDGE  640000
#define B      64

// xt[i*B + b] = alpha[i] * x[b*N_IN + i]   (tile transpose, coalesced both sides)
__global__ void scale_transpose_kernel(const float* __restrict__ x,
                                       const float* __restrict__ alpha,
                                       float* __restrict__ xt) {
    __shared__ float tile[64][65];
    const int i0 = blockIdx.x * 64;
    const int tx = threadIdx.x & 63;   // 0..63
    const int ty = threadIdx.x >> 6;   // 0..3
    const int i  = i0 + tx;
    const float a = (i < N_IN) ? alpha[i] : 0.0f;
    #pragma unroll
    for (int k = 0; k < 16; ++k) {
        const int b = ty + (k << 2);
        tile[b][tx] = (i < N_IN) ? a * x[(size_t)b * N_IN + i] : 0.0f;
    }
    __syncthreads();
    #pragma unroll
    for (int k = 0; k < 16; ++k) {
        const int ii = ty + (k << 2);
        const int gi = i0 + ii;
        if (gi < N_IN) xt[(size_t)gi * B + tx] = tile[tx][ii];
    }
}

// One wave per edge, one lane per batch element.
// yt[dst*B + lane] += exp(-||pi-po||^2/sigma^2) * xt[src*B + lane]
__global__ void edge_kernel(const int* __restrict__ edge,
                            const float* __restrict__ sigma,
                            const float* __restrict__ ipos,
                            const float* __restrict__ opos,
                            const float* __restrict__ xt,
                            float* __restrict__ yt) {
    const int wid  = threadIdx.x >> 6;
    const int lane = threadIdx.x & 63;
    const int e    = blockIdx.x * 4 + wid;
    if (e >= NEDGE) return;

    const int dst = edge[e];
    const int src = edge[NEDGE + e];

    const float dx = ipos[src * 3 + 0] - opos[dst * 3 + 0];
    const float dy = ipos[src * 3 + 1] - opos[dst * 3 + 1];
    const float dz = ipos[src * 3 + 2] - opos[dst * 3 + 2];
    const float sg = sigma[src];
    const float w  = __expf(-(dx * dx + dy * dy + dz * dz) / (sg * sg));

    const float val = w * xt[(size_t)src * B + lane];
    atomicAdd(&yt[(size_t)dst * B + lane], val);
}

// y[b*N_OUT + i] = yt[i*B + b]   (tile transpose)
__global__ void out_transpose_kernel(const float* __restrict__ yt,
                                     float* __restrict__ y) {
    __shared__ float tile[64][65];
    const int i0 = blockIdx.x * 64;
    const int tx = threadIdx.x & 63;
    const int ty = threadIdx.x >> 6;
    #pragma unroll
    for (int k = 0; k < 16; ++k) {
        const int ii = ty + (k << 2);
        const int gi = i0 + ii;
        tile[ii][tx] = (gi < N_OUT) ? yt[(size_t)gi * B + tx] : 0.0f;
    }
    __syncthreads();
    const int gi = i0 + tx;
    if (gi < N_OUT) {
        #pragma unroll
        for (int k = 0; k < 16; ++k) {
            const int b = ty + (k << 2);
            y[(size_t)b * N_OUT + gi] = tile[tx][b];
        }
    }
}

extern "C" void kernel_launch(void* const* d_in, const int* in_sizes, int n_in,
                              void* d_out, int out_size, void* d_ws, size_t ws_size,
                              hipStream_t stream) {
    const float* x     = (const float*)d_in[0];
    const float* alpha = (const float*)d_in[1];
    const float* sigma = (const float*)d_in[2];
    const float* ipos  = (const float*)d_in[3];
    const float* opos  = (const float*)d_in[4];
    const int*   edge  = (const int*)d_in[5];
    float* y = (float*)d_out;

    float* xt = (float*)d_ws;                    // N_IN * B floats  (5.12 MB)
    float* yt = xt + (size_t)N_IN * B;           // N_OUT * B floats (5.12 MB)

    hipMemsetAsync(yt, 0, (size_t)N_OUT * B * sizeof(float), stream);

    scale_transpose_kernel<<<(N_IN + 63) / 64, 256, 0, stream>>>(x, alpha, xt);
    edge_kernel<<<(NEDGE + 3) / 4, 256, 0, stream>>>(edge, sigma, ipos, opos, xt, yt);
    out_transpose_kernel<<<(N_OUT + 63) / 64, 256, 0, stream>>>(yt, y);
}

// Round 2
// 157.777 us; speedup vs baseline: 1.0667x; 1.0667x over previous
//
#include <hip/hip_runtime.h>

#define N_IN   20000
#define N_OUT  20000
#define NEDGE  640000
#define B      64

// xt[i*B + b] = alpha[i] * x[b*N_IN + i]   (tile transpose, coalesced both sides)
__global__ void scale_transpose_kernel(const float* __restrict__ x,
                                       const float* __restrict__ alpha,
                                       float* __restrict__ xt) {
    __shared__ float tile[64][65];
    const int i0 = blockIdx.x * 64;
    const int tx = threadIdx.x & 63;   // 0..63
    const int ty = threadIdx.x >> 6;   // 0..3
    const int i  = i0 + tx;
    const float a = (i < N_IN) ? alpha[i] : 0.0f;
    #pragma unroll
    for (int k = 0; k < 16; ++k) {
        const int b = ty + (k << 2);
        tile[b][tx] = (i < N_IN) ? a * x[(size_t)b * N_IN + i] : 0.0f;
    }
    __syncthreads();
    #pragma unroll
    for (int k = 0; k < 16; ++k) {
        const int ii = ty + (k << 2);
        const int gi = i0 + ii;
        if (gi < N_IN) xt[(size_t)gi * B + tx] = tile[tx][ii];
    }
}

// Histogram of dst
__global__ void hist_kernel(const int* __restrict__ edge, int* __restrict__ bins) {
    const int e = blockIdx.x * 256 + threadIdx.x;
    if (e >= NEDGE) return;
    atomicAdd(&bins[edge[e]], 1);
}

// Single-block exclusive scan of 20000 bins -> off[0..N_OUT] and cursor copy
__global__ void scan_kernel(const int* __restrict__ bins,
                            int* __restrict__ off,
                            int* __restrict__ cursor) {
    __shared__ int partial[1024];
    const int t = threadIdx.x;
    const int CH = 20;                       // 1024*20 = 20480 >= 20000
    const int base = t * CH;
    int local[CH];
    int s = 0;
    #pragma unroll
    for (int j = 0; j < CH; ++j) {
        const int idx = base + j;
        const int v = (idx < N_OUT) ? bins[idx] : 0;
        local[j] = s;
        s += v;
    }
    partial[t] = s;
    __syncthreads();
    // Hillis-Steele inclusive scan over 1024 partials
    for (int d = 1; d < 1024; d <<= 1) {
        const int v = (t >= d) ? partial[t - d] : 0;
        __syncthreads();
        partial[t] += v;
        __syncthreads();
    }
    const int excl = (t > 0) ? partial[t - 1] : 0;
    #pragma unroll
    for (int j = 0; j < CH; ++j) {
        const int idx = base + j;
        if (idx < N_OUT) {
            const int o = excl + local[j];
            off[idx] = o;
            cursor[idx] = o;
        }
    }
    if (t == 0) off[N_OUT] = NEDGE;
}

// Scatter edges into CSR order; precompute RBF weight per edge.
// srcw[pos] = (src as int bits, w)
__global__ void scatter_kernel(const int* __restrict__ edge,
                               const float* __restrict__ sigma,
                               const float* __restrict__ ipos,
                               const float* __restrict__ opos,
                               int* __restrict__ cursor,
                               float2* __restrict__ srcw) {
    const int e = blockIdx.x * 256 + threadIdx.x;
    if (e >= NEDGE) return;
    const int dst = edge[e];
    const int src = edge[NEDGE + e];

    const float dx = ipos[src * 3 + 0] - opos[dst * 3 + 0];
    const float dy = ipos[src * 3 + 1] - opos[dst * 3 + 1];
    const float dz = ipos[src * 3 + 2] - opos[dst * 3 + 2];
    const float sg = sigma[src];
    const float w  = __expf(-(dx * dx + dy * dy + dz * dz) / (sg * sg));

    const int pos = atomicAdd(&cursor[dst], 1);
    srcw[pos] = make_float2(__int_as_float(src), w);
}

// One wave per dst node; lane = batch element; register accumulation.
__global__ void gather_kernel(const int* __restrict__ off,
                              const float2* __restrict__ srcw,
                              const float* __restrict__ xt,
                              float* __restrict__ yt) {
    const int wid  = threadIdx.x >> 6;
    const int lane = threadIdx.x & 63;
    const int d = blockIdx.x * 4 + wid;
    if (d >= N_OUT) return;

    int k = off[d];
    const int end = off[d + 1];
    float acc = 0.0f;
    for (; k + 2 <= end; k += 2) {
        const float2 sw0 = srcw[k];
        const float2 sw1 = srcw[k + 1];
        const float v0 = xt[(size_t)__float_as_int(sw0.x) * B + lane];
        const float v1 = xt[(size_t)__float_as_int(sw1.x) * B + lane];
        acc = fmaf(sw0.y, v0, acc);
        acc = fmaf(sw1.y, v1, acc);
    }
    if (k < end) {
        const float2 sw = srcw[k];
        acc = fmaf(sw.y, xt[(size_t)__float_as_int(sw.x) * B + lane], acc);
    }
    yt[(size_t)d * B + lane] = acc;
}

// y[b*N_OUT + i] = yt[i*B + b]   (tile transpose)
__global__ void out_transpose_kernel(const float* __restrict__ yt,
                                     float* __restrict__ y) {
    __shared__ float tile[64][65];
    const int i0 = blockIdx.x * 64;
    const int tx = threadIdx.x & 63;
    const int ty = threadIdx.x >> 6;
    #pragma unroll
    for (int k = 0; k < 16; ++k) {
        const int ii = ty + (k << 2);
        const int gi = i0 + ii;
        tile[ii][tx] = (gi < N_OUT) ? yt[(size_t)gi * B + tx] : 0.0f;
    }
    __syncthreads();
    const int gi = i0 + tx;
    if (gi < N_OUT) {
        #pragma unroll
        for (int k = 0; k < 16; ++k) {
            const int b = ty + (k << 2);
            y[(size_t)b * N_OUT + gi] = tile[tx][b];
        }
    }
}

extern "C" void kernel_launch(void* const* d_in, const int* in_sizes, int n_in,
                              void* d_out, int out_size, void* d_ws, size_t ws_size,
                              hipStream_t stream) {
    const float* x     = (const float*)d_in[0];
    const float* alpha = (const float*)d_in[1];
    const float* sigma = (const float*)d_in[2];
    const float* ipos  = (const float*)d_in[3];
    const float* opos  = (const float*)d_in[4];
    const int*   edge  = (const int*)d_in[5];
    float* y = (float*)d_out;

    // workspace layout
    float*  xt     = (float*)d_ws;                       // N_IN*B floats   (5.12 MB)
    float*  yt     = xt + (size_t)N_IN * B;              // N_OUT*B floats  (5.12 MB)
    float2* srcw   = (float2*)(yt + (size_t)N_OUT * B);  // NEDGE float2    (5.12 MB)
    int*    off    = (int*)(srcw + NEDGE);               // N_OUT+1 ints
    int*    cursor = off + (N_OUT + 1);                  // N_OUT ints
    int*    bins   = cursor + N_OUT;                     // N_OUT ints

    hipMemsetAsync(bins, 0, N_OUT * sizeof(int), stream);

    scale_transpose_kernel<<<(N_IN + 63) / 64, 256, 0, stream>>>(x, alpha, xt);
    hist_kernel<<<(NEDGE + 255) / 256, 256, 0, stream>>>(edge, bins);
    scan_kernel<<<1, 1024, 0, stream>>>(bins, off, cursor);
    scatter_kernel<<<(NEDGE + 255) / 256, 256, 0, stream>>>(edge, sigma, ipos, opos, cursor, srcw);
    gather_kernel<<<(N_OUT + 3) / 4, 256, 0, stream>>>(off, srcw, xt, yt);
    out_transpose_kernel<<<(N_OUT + 63) / 64, 256, 0, stream>>>(yt, y);
}

// Round 3
// 137.987 us; speedup vs baseline: 1.2197x; 1.1434x over previous
//
#include <hip/hip_runtime.h>

#define N_IN   20000
#define N_OUT  20000
#define NEDGE  640000
#define B      64

// xt[i*B + b] = alpha[i] * x[b*N_IN + i]   (tile transpose, coalesced both sides)
// Also zeroes bins[] (runs strictly before hist_kernel in stream order).
__global__ void scale_transpose_kernel(const float* __restrict__ x,
                                       const float* __restrict__ alpha,
                                       float* __restrict__ xt,
                                       int* __restrict__ bins) {
    // zero the histogram bins: 313 blocks * 64 >= 20000
    const int zb = blockIdx.x * 64 + (threadIdx.x & 63);
    if (threadIdx.x < 64 && zb < N_OUT) bins[zb] = 0;

    __shared__ float tile[64][65];
    const int i0 = blockIdx.x * 64;
    const int tx = threadIdx.x & 63;   // 0..63
    const int ty = threadIdx.x >> 6;   // 0..3
    const int i  = i0 + tx;
    const float a = (i < N_IN) ? alpha[i] : 0.0f;
    #pragma unroll
    for (int k = 0; k < 16; ++k) {
        const int b = ty + (k << 2);
        tile[b][tx] = (i < N_IN) ? a * x[(size_t)b * N_IN + i] : 0.0f;
    }
    __syncthreads();
    #pragma unroll
    for (int k = 0; k < 16; ++k) {
        const int ii = ty + (k << 2);
        const int gi = i0 + ii;
        if (gi < N_IN) xt[(size_t)gi * B + tx] = tile[tx][ii];
    }
}

// Histogram of dst
__global__ void hist_kernel(const int* __restrict__ edge, int* __restrict__ bins) {
    const int e = blockIdx.x * 256 + threadIdx.x;
    if (e >= NEDGE) return;
    atomicAdd(&bins[edge[e]], 1);
}

// Single-block exclusive scan of 20000 bins -> off[0..N_OUT] and cursor copy
__global__ void scan_kernel(const int* __restrict__ bins,
                            int* __restrict__ off,
                            int* __restrict__ cursor) {
    __shared__ int partial[1024];
    const int t = threadIdx.x;
    const int CH = 20;                       // 1024*20 = 20480 >= 20000
    const int base = t * CH;
    int local[CH];
    int s = 0;
    #pragma unroll
    for (int j = 0; j < CH; ++j) {
        const int idx = base + j;
        const int v = (idx < N_OUT) ? bins[idx] : 0;
        local[j] = s;
        s += v;
    }
    partial[t] = s;
    __syncthreads();
    // Hillis-Steele inclusive scan over 1024 partials
    for (int d = 1; d < 1024; d <<= 1) {
        const int v = (t >= d) ? partial[t - d] : 0;
        __syncthreads();
        partial[t] += v;
        __syncthreads();
    }
    const int excl = (t > 0) ? partial[t - 1] : 0;
    #pragma unroll
    for (int j = 0; j < CH; ++j) {
        const int idx = base + j;
        if (idx < N_OUT) {
            const int o = excl + local[j];
            off[idx] = o;
            cursor[idx] = o;
        }
    }
    if (t == 0) off[N_OUT] = NEDGE;
}

// Scatter edges into CSR order; precompute RBF weight per edge.
// srcw[pos] = (src as int bits, w)
__global__ void scatter_kernel(const int* __restrict__ edge,
                               const float* __restrict__ sigma,
                               const float* __restrict__ ipos,
                               const float* __restrict__ opos,
                               int* __restrict__ cursor,
                               float2* __restrict__ srcw) {
    const int e = blockIdx.x * 256 + threadIdx.x;
    if (e >= NEDGE) return;
    const int dst = edge[e];
    const int src = edge[NEDGE + e];

    const float dx = ipos[src * 3 + 0] - opos[dst * 3 + 0];
    const float dy = ipos[src * 3 + 1] - opos[dst * 3 + 1];
    const float dz = ipos[src * 3 + 2] - opos[dst * 3 + 2];
    const float sg = sigma[src];
    const float w  = __expf(-(dx * dx + dy * dy + dz * dz) / (sg * sg));

    const int pos = atomicAdd(&cursor[dst], 1);
    srcw[pos] = make_float2(__int_as_float(src), w);
}

// One wave per dst node; lane = batch element; register accumulation.
__global__ void gather_kernel(const int* __restrict__ off,
                              const float2* __restrict__ srcw,
                              const float* __restrict__ xt,
                              float* __restrict__ yt) {
    const int wid  = threadIdx.x >> 6;
    const int lane = threadIdx.x & 63;
    const int d = blockIdx.x * 4 + wid;
    if (d >= N_OUT) return;

    int k = off[d];
    const int end = off[d + 1];
    float acc0 = 0.0f, acc1 = 0.0f;
    for (; k + 4 <= end; k += 4) {
        const float2 sw0 = srcw[k];
        const float2 sw1 = srcw[k + 1];
        const float2 sw2 = srcw[k + 2];
        const float2 sw3 = srcw[k + 3];
        const float v0 = xt[(size_t)__float_as_int(sw0.x) * B + lane];
        const float v1 = xt[(size_t)__float_as_int(sw1.x) * B + lane];
        const float v2 = xt[(size_t)__float_as_int(sw2.x) * B + lane];
        const float v3 = xt[(size_t)__float_as_int(sw3.x) * B + lane];
        acc0 = fmaf(sw0.y, v0, acc0);
        acc1 = fmaf(sw1.y, v1, acc1);
        acc0 = fmaf(sw2.y, v2, acc0);
        acc1 = fmaf(sw3.y, v3, acc1);
    }
    for (; k < end; ++k) {
        const float2 sw = srcw[k];
        acc0 = fmaf(sw.y, xt[(size_t)__float_as_int(sw.x) * B + lane], acc0);
    }
    yt[(size_t)d * B + lane] = acc0 + acc1;
}

// y[b*N_OUT + i] = yt[i*B + b]   (tile transpose)
__global__ void out_transpose_kernel(const float* __restrict__ yt,
                                     float* __restrict__ y) {
    __shared__ float tile[64][65];
    const int i0 = blockIdx.x * 64;
    const int tx = threadIdx.x & 63;
    const int ty = threadIdx.x >> 6;
    #pragma unroll
    for (int k = 0; k < 16; ++k) {
        const int ii = ty + (k << 2);
        const int gi = i0 + ii;
        tile[ii][tx] = (gi < N_OUT) ? yt[(size_t)gi * B + tx] : 0.0f;
    }
    __syncthreads();
    const int gi = i0 + tx;
    if (gi < N_OUT) {
        #pragma unroll
        for (int k = 0; k < 16; ++k) {
            const int b = ty + (k << 2);
            y[(size_t)b * N_OUT + gi] = tile[tx][b];
        }
    }
}

extern "C" void kernel_launch(void* const* d_in, const int* in_sizes, int n_in,
                              void* d_out, int out_size, void* d_ws, size_t ws_size,
                              hipStream_t stream) {
    const float* x     = (const float*)d_in[0];
    const float* alpha = (const float*)d_in[1];
    const float* sigma = (const float*)d_in[2];
    const float* ipos  = (const float*)d_in[3];
    const float* opos  = (const float*)d_in[4];
    const int*   edge  = (const int*)d_in[5];
    float* y = (float*)d_out;

    // workspace layout
    float*  xt     = (float*)d_ws;                       // N_IN*B floats   (5.12 MB)
    float*  yt     = xt + (size_t)N_IN * B;              // N_OUT*B floats  (5.12 MB)
    float2* srcw   = (float2*)(yt + (size_t)N_OUT * B);  // NEDGE float2    (5.12 MB)
    int*    off    = (int*)(srcw + NEDGE);               // N_OUT+1 ints
    int*    cursor = off + (N_OUT + 1);                  // N_OUT ints
    int*    bins   = cursor + N_OUT;                     // N_OUT ints

    scale_transpose_kernel<<<(N_IN + 63) / 64, 256, 0, stream>>>(x, alpha, xt, bins);
    hist_kernel<<<(NEDGE + 255) / 256, 256, 0, stream>>>(edge, bins);
    scan_kernel<<<1, 1024, 0, stream>>>(bins, off, cursor);
    scatter_kernel<<<(NEDGE + 255) / 256, 256, 0, stream>>>(edge, sigma, ipos, opos, cursor, srcw);
    gather_kernel<<<(N_OUT + 3) / 4, 256, 0, stream>>>(off, srcw, xt, yt);
    out_transpose_kernel<<<(N_OUT + 63) / 64, 256, 0, stream>>>(yt, y);
}